// Round 5
// baseline (395.096 us; speedup 1.0000x reference)
//
#include <hip/hip_runtime.h>
#include <hip/hip_bf16.h>

#define N_NODES 50000
#define N_EDGES 1600000
#define NREL    16
#define DIM     64

#define BKT_SH  4
#define BKT_SZ  16
#define NBKT    3125          // 50000/16 exact
#define NKEY    (NBKT * 16)   // 50000 (tile,rel) segments
#define SEG_PAD 544
#define EMAX    (N_EDGES + NBKT * SEG_PAD + 2048)   // 3,302,048 edge slots
#define PREP_HBLK 3125        // 3.2M h elems / 1024 per block

typedef __attribute__((ext_vector_type(8))) short short8;
typedef __attribute__((ext_vector_type(4))) float float4v;
typedef __attribute__((ext_vector_type(4))) unsigned short ushort4v;

template<int IS_F32>
__device__ __forceinline__ float ldx(const void* p, size_t i) {
    if (IS_F32) {
        return ((const float*)p)[i];
    } else {
        unsigned short u = ((const unsigned short*)p)[i];
        return __uint_as_float(((unsigned)u) << 16);
    }
}

__device__ __forceinline__ float bfbits2f(unsigned short u) {
    return __uint_as_float(((unsigned)u) << 16);
}

__device__ __forceinline__ unsigned short f2bfbits(float v) {
    __hip_bfloat16 b = __float2bfloat16(v);
    unsigned short us; __builtin_memcpy(&us, &b, 2);
    return us;
}

// ---------------------------------------------------------------------------
// Dtype detector (proven): flag=1 if f32 dataset, 0 if bf16.
// ---------------------------------------------------------------------------
__global__ __launch_bounds__(1024) void k_detect(
    const float* __restrict__ norm_f, int* __restrict__ flag)
{
    __shared__ int sbad;
    if (threadIdx.x == 0) sbad = 0;
    __syncthreads();
    float v = norm_f[threadIdx.x];
    int bad = (v != v || fabsf(v) > 1e3f) ? 1 : 0;
    if (bad) atomicOr(&sbad, 1);
    __syncthreads();
    if (threadIdx.x == 0) *flag = sbad ? 0 : 1;
}

// ---------------------------------------------------------------------------
// K_ZERO: clear cnt/cur counters and packed2/normS (pad entries must be 0:
// norm=0 nulls the MFMA selector column; src=0 keeps the gather in-bounds).
// ---------------------------------------------------------------------------
__global__ __launch_bounds__(256) void k_zero(
    uint4* __restrict__ packed2, uint4* __restrict__ normS,
    uint4* __restrict__ cnt, uint4* __restrict__ cur)
{
    const int stride = gridDim.x * 256;
    const int t0 = blockIdx.x * 256 + threadIdx.x;
    const uint4 z = {0u, 0u, 0u, 0u};
    for (int i = t0; i < (int)(EMAX * 4 / 16); i += stride) packed2[i] = z;
    for (int i = t0; i < (int)(EMAX * 2 / 16); i += stride) normS[i]   = z;
    for (int i = t0; i < (int)(NKEY * 4 / 16); i += stride) cnt[i]     = z;
    for (int i = t0; i < (int)(NKEY * 4 / 16); i += stride) cur[i]     = z;
}

// ---------------------------------------------------------------------------
// K_CNT: histogram over 50K (tile,rel) keys via global atomics.
// key = (dst & ~15) + rel.
// ---------------------------------------------------------------------------
__global__ __launch_bounds__(256) void k_cnt(
    const int* __restrict__ dst, const int* __restrict__ rel,
    int* __restrict__ cnt)
{
    const int stride = gridDim.x * 256;
    for (int e = blockIdx.x * 256 + threadIdx.x; e < N_EDGES; e += stride)
        atomicAdd(&cnt[(dst[e] & ~(BKT_SZ - 1)) + rel[e]], 1);
}

// ---------------------------------------------------------------------------
// K_SCAN: single-block exclusive scan of pad-32 counts -> segBase.
// 50K elements, 1024 threads, 49 chunks.
// ---------------------------------------------------------------------------
__global__ __launch_bounds__(1024) void k_scan(
    const int* __restrict__ cnt, int* __restrict__ segBase)
{
    __shared__ int wsumI[16];
    __shared__ int carry_s;
    const int tid = threadIdx.x;
    const int lane = tid & 63, wid = tid >> 6;
    if (tid == 0) carry_s = 0;
    __syncthreads();
    for (int chunk = 0; chunk < (NKEY + 1023) / 1024; ++chunk) {
        int i = chunk * 1024 + tid;
        int c = (i < NKEY) ? ((cnt[i] + 31) & ~31) : 0;
        int incl = c;
#pragma unroll
        for (int off = 1; off < 64; off <<= 1) {
            int t = __shfl_up(incl, off, 64);
            if (lane >= off) incl += t;
        }
        if (lane == 63) wsumI[wid] = incl;
        __syncthreads();
        if (tid < 16) {
            int si = wsumI[tid];
#pragma unroll
            for (int off = 1; off < 16; off <<= 1) {
                int t = __shfl_up(si, off, 64);
                if (tid >= off) si += t;
            }
            wsumI[tid] = si;   // inclusive scan of wave sums
        }
        __syncthreads();
        int base_w = (wid > 0) ? wsumI[wid - 1] : 0;
        int excl = carry_s + base_w + incl - c;
        if (i < NKEY) segBase[i] = excl;
        int total = wsumI[15];
        __syncthreads();   // everyone done reading carry_s/wsumI
        if (tid == 0) carry_s += total;
        __syncthreads();
    }
    if (tid == 0) segBase[NKEY] = carry_s;
}

// ---------------------------------------------------------------------------
// K_PLACE: direct placement. Order within a segment is irrelevant (sum), so
// a bare atomic cursor suffices — no multisplit, no R round-trip.
// ---------------------------------------------------------------------------
template<int IS_F32>
__device__ __forceinline__ void place_body(
    const int* __restrict__ src, const int* __restrict__ dst,
    const int* __restrict__ rel, const void* __restrict__ norm_raw,
    const int* __restrict__ segBase, int* __restrict__ cur,
    unsigned* __restrict__ packed2, unsigned short* __restrict__ normS)
{
    const int stride = gridDim.x * 256;
    for (int e = blockIdx.x * 256 + threadIdx.x; e < N_EDGES; e += stride) {
        int d = dst[e];
        int key = (d & ~(BKT_SZ - 1)) + rel[e];
        int pos = segBase[key] + atomicAdd(&cur[key], 1);
        packed2[pos] = (unsigned)(d & (BKT_SZ - 1)) | ((unsigned)src[e] << 8);
        normS[pos]   = f2bfbits(ldx<IS_F32>(norm_raw, e));
    }
}

__global__ __launch_bounds__(256) void k_place(
    const int* __restrict__ src, const int* __restrict__ dst,
    const int* __restrict__ rel, const void* __restrict__ norm_raw,
    const int* __restrict__ segBase, int* __restrict__ cur,
    unsigned* __restrict__ packed2, unsigned short* __restrict__ normS,
    const int* __restrict__ flag)
{
    if (*flag) place_body<1>(src, dst, rel, norm_raw, segBase, cur, packed2, normS);
    else       place_body<0>(src, dst, rel, norm_raw, segBase, cur, packed2, normS);
}

// ---------------------------------------------------------------------------
// PREP (proven): h -> bf16 copy (6.4 MB gather target) and W -> pre-swizzled
// bf16 B-fragment layout (stride 40).
// ---------------------------------------------------------------------------
__global__ __launch_bounds__(256) void k_prep(
    const void* __restrict__ h_raw, const void* __restrict__ w_raw,
    unsigned short* __restrict__ hbf, unsigned short* __restrict__ Wswz,
    const int* __restrict__ flag)
{
    const int f = *flag;
    const int blk = blockIdx.x;
    if (blk < PREP_HBLK) {
        int i0 = blk * 1024 + threadIdx.x * 4;
        if (f) {
            float4 v = *(const float4*)((const float*)h_raw + i0);
            ushort4v o;
            o[0] = f2bfbits(v.x); o[1] = f2bfbits(v.y);
            o[2] = f2bfbits(v.z); o[3] = f2bfbits(v.w);
            *(ushort4v*)(hbf + i0) = o;
        } else {
            *(uint2*)(hbf + i0) = *(const uint2*)((const unsigned short*)h_raw + i0);
        }
    } else {
        int rel = blk - PREP_HBLK;
        for (int idx = threadIdx.x; idx < 4096; idx += 256) {
            int d = idx >> 6, o = idx & 63;
            float wv = f ? ((const float*)w_raw)[(size_t)((rel << 6) + d) * 64 + o]
                         : bfbits2f(((const unsigned short*)w_raw)[(size_t)((rel << 6) + d) * 64 + o]);
            int c = d >> 5, q = (d >> 3) & 3, j = d & 7;
            Wswz[(size_t)rel * 5120 + ((c << 6) + o) * 40 + q * 8 + j] = f2bfbits(wv);
        }
    }
}

// ---------------------------------------------------------------------------
// K_FUSED2 (proven in R4, byte-identical): one wave per 16-dst tile.
//   s[16x64] = sum_chunks P[16x32] x H[32x64]   (P = norm selector; MFMA does
//   the dst-scatter; H rows gathered as 2B loads from 6.4MB L2-scale hbf)
//   out_tile += s @ W_r                          (8 MFMAs, reg accumulation)
// Zero atomics.
// ---------------------------------------------------------------------------
#define MFMA_BF16 __builtin_amdgcn_mfma_f32_16x16x32_bf16

__global__ __launch_bounds__(256) void k_fused2(
    const unsigned* __restrict__ packed2,
    const unsigned short* __restrict__ normS,
    const unsigned short* __restrict__ hbf,
    const unsigned short* __restrict__ Wswz,
    const int* __restrict__ segBase,
    const int* __restrict__ segCnt,
    void* __restrict__ out, const int* __restrict__ flag)
{
    __shared__ __align__(16) unsigned short sbuf[4][16 * 72];
    const int tid  = threadIdx.x;
    const int lane = tid & 63, wave = tid >> 6;
    const int n15  = lane & 15, quad = lane >> 4;
    const int tile = blockIdx.x * 4 + wave;
    if (tile >= NBKT) return;

    float4v ac0 = {0.f,0.f,0.f,0.f}, ac1 = {0.f,0.f,0.f,0.f};
    float4v ac2 = {0.f,0.f,0.f,0.f}, ac3 = {0.f,0.f,0.f,0.f};
    unsigned short* sb_ = &sbuf[wave][0];

    for (int r = 0; r < NREL; ++r) {
        const int sgb  = segBase[tile * 16 + r];
        const int scnt = segCnt[tile * 16 + r];
        if (scnt == 0) continue;
        const int nch = (scnt + 31) >> 5;

        float4v s0 = {0.f,0.f,0.f,0.f}, s1 = {0.f,0.f,0.f,0.f};
        float4v s2 = {0.f,0.f,0.f,0.f}, s3 = {0.f,0.f,0.f,0.f};

        for (int c = 0; c < nch; ++c) {
            const int e0 = sgb + (c << 5) + (quad << 3);
            const uint4 pa = *(const uint4*)(packed2 + e0);
            const uint4 pb = *(const uint4*)(packed2 + e0 + 4);
            const ushort4v na = *(const ushort4v*)(normS + e0);
            const ushort4v nb = *(const ushort4v*)(normS + e0 + 4);

            const unsigned short* h0 = hbf + (size_t)(pa.x >> 8) * 64 + n15;
            const unsigned short* h1 = hbf + (size_t)(pa.y >> 8) * 64 + n15;
            const unsigned short* h2 = hbf + (size_t)(pa.z >> 8) * 64 + n15;
            const unsigned short* h3 = hbf + (size_t)(pa.w >> 8) * 64 + n15;
            const unsigned short* h4 = hbf + (size_t)(pb.x >> 8) * 64 + n15;
            const unsigned short* h5 = hbf + (size_t)(pb.y >> 8) * 64 + n15;
            const unsigned short* h6 = hbf + (size_t)(pb.z >> 8) * 64 + n15;
            const unsigned short* h7 = hbf + (size_t)(pb.w >> 8) * 64 + n15;

            short8 av;
            av[0] = ((int)(pa.x & 15u) == n15) ? (short)na[0] : (short)0;
            av[1] = ((int)(pa.y & 15u) == n15) ? (short)na[1] : (short)0;
            av[2] = ((int)(pa.z & 15u) == n15) ? (short)na[2] : (short)0;
            av[3] = ((int)(pa.w & 15u) == n15) ? (short)na[3] : (short)0;
            av[4] = ((int)(pb.x & 15u) == n15) ? (short)nb[0] : (short)0;
            av[5] = ((int)(pb.y & 15u) == n15) ? (short)nb[1] : (short)0;
            av[6] = ((int)(pb.z & 15u) == n15) ? (short)nb[2] : (short)0;
            av[7] = ((int)(pb.w & 15u) == n15) ? (short)nb[3] : (short)0;

#define GATHER_MFMA(S, OFF) \
            { short8 bv; \
              bv[0] = (short)h0[OFF]; bv[1] = (short)h1[OFF]; \
              bv[2] = (short)h2[OFF]; bv[3] = (short)h3[OFF]; \
              bv[4] = (short)h4[OFF]; bv[5] = (short)h5[OFF]; \
              bv[6] = (short)h6[OFF]; bv[7] = (short)h7[OFF]; \
              S = MFMA_BF16(av, bv, S, 0, 0, 0); }

            GATHER_MFMA(s0, 0)
            GATHER_MFMA(s1, 16)
            GATHER_MFMA(s2, 32)
            GATHER_MFMA(s3, 48)
#undef GATHER_MFMA
        }

        // repack s (C layout: row=quad*4+i, col=t*16+n15) -> LDS row-major
#pragma unroll
        for (int i = 0; i < 4; ++i) {
            sb_[(quad * 4 + i) * 72 +  0 + n15] = f2bfbits(s0[i]);
            sb_[(quad * 4 + i) * 72 + 16 + n15] = f2bfbits(s1[i]);
            sb_[(quad * 4 + i) * 72 + 32 + n15] = f2bfbits(s2[i]);
            sb_[(quad * 4 + i) * 72 + 48 + n15] = f2bfbits(s3[i]);
        }

        // A-frags: row=n15, k-chunk=quad (k1-proven layout)
        const short8 a0 = *(const short8*)(sb_ + n15 * 72 + quad * 8);
        const short8 a1 = *(const short8*)(sb_ + n15 * 72 + 32 + quad * 8);

        const unsigned short* wp = Wswz + (size_t)r * 5120;
        const short8 w00 = *(const short8*)(wp + ( 0 + n15) * 40 + quad * 8);
        const short8 w01 = *(const short8*)(wp + (16 + n15) * 40 + quad * 8);
        const short8 w02 = *(const short8*)(wp + (32 + n15) * 40 + quad * 8);
        const short8 w03 = *(const short8*)(wp + (48 + n15) * 40 + quad * 8);
        const short8 w10 = *(const short8*)(wp + (64 + n15) * 40 + quad * 8);
        const short8 w11 = *(const short8*)(wp + (80 + n15) * 40 + quad * 8);
        const short8 w12 = *(const short8*)(wp + (96 + n15) * 40 + quad * 8);
        const short8 w13 = *(const short8*)(wp + (112 + n15) * 40 + quad * 8);

        ac0 = MFMA_BF16(a0, w00, ac0, 0, 0, 0);
        ac1 = MFMA_BF16(a0, w01, ac1, 0, 0, 0);
        ac2 = MFMA_BF16(a0, w02, ac2, 0, 0, 0);
        ac3 = MFMA_BF16(a0, w03, ac3, 0, 0, 0);
        ac0 = MFMA_BF16(a1, w10, ac0, 0, 0, 0);
        ac1 = MFMA_BF16(a1, w11, ac1, 0, 0, 0);
        ac2 = MFMA_BF16(a1, w12, ac2, 0, 0, 0);
        ac3 = MFMA_BF16(a1, w13, ac3, 0, 0, 0);
    }

    const int node0 = tile << 4;
    const int f = *flag;
#define STORE_T(AC, T) \
    { \
        _Pragma("unroll") \
        for (int i = 0; i < 4; ++i) { \
            float rv = fmaxf(AC[i], 0.f); \
            size_t ob = (size_t)(node0 + quad * 4 + i) * 64 + (T) * 16 + n15; \
            if (f) ((float*)out)[ob] = rv; \
            else   ((unsigned short*)out)[ob] = f2bfbits(rv); \
        } \
    }
    STORE_T(ac0, 0)
    STORE_T(ac1, 1)
    STORE_T(ac2, 2)
    STORE_T(ac3, 3)
#undef STORE_T
}

// ---------------------------------------------------------------------------
extern "C" void kernel_launch(void* const* d_in, const int* in_sizes, int n_in,
                              void* d_out, int out_size, void* d_ws, size_t ws_size,
                              hipStream_t stream)
{
    const void* h      = d_in[0];
    const void* weight = d_in[1];
    const void* norm   = d_in[2];
    const int* src = (const int*)d_in[3];
    const int* dst = (const int*)d_in[4];
    const int* rel = (const int*)d_in[5];

    char* w = (char*)d_ws;
    int* flag = (int*)w;                        w += 256;
    int* cnt  = (int*)w;                        w += ((size_t)NKEY * 4 + 255) / 256 * 256;
    int* cur  = (int*)w;                        w += ((size_t)NKEY * 4 + 255) / 256 * 256;
    int* segBase = (int*)w;                     w += ((size_t)(NKEY + 1) * 4 + 255) / 256 * 256;
    unsigned* packed2 = (unsigned*)w;           w += ((size_t)EMAX * 4 + 255) / 256 * 256;
    unsigned short* normS = (unsigned short*)w; w += ((size_t)EMAX * 2 + 255) / 256 * 256;
    unsigned short* hbf = (unsigned short*)w;   w += (size_t)N_NODES * DIM * 2;
    unsigned short* Wswz = (unsigned short*)w;  w += (size_t)NREL * 5120 * 2;

    k_detect<<<1, 1024, 0, stream>>>((const float*)norm, flag);

    k_zero<<<2048, 256, 0, stream>>>((uint4*)packed2, (uint4*)normS,
                                     (uint4*)cnt, (uint4*)cur);

    k_cnt<<<2048, 256, 0, stream>>>(dst, rel, cnt);

    k_scan<<<1, 1024, 0, stream>>>(cnt, segBase);

    k_place<<<2048, 256, 0, stream>>>(src, dst, rel, norm,
                                      segBase, cur, packed2, normS, flag);

    k_prep<<<PREP_HBLK + NREL, 256, 0, stream>>>(h, weight, hbf, Wswz, flag);

    k_fused2<<<(NBKT + 3) / 4, 256, 0, stream>>>(packed2, normS, hbf, Wswz,
                                                 segBase, cnt, d_out, flag);
}

// Round 6
// 232.619 us; speedup vs baseline: 1.6985x; 1.6985x over previous
//
#include <hip/hip_runtime.h>
#include <hip/hip_bf16.h>

#define N_NODES 50000
#define N_EDGES 1600000
#define NREL    16
#define DIM     64

#define BKT_SZ  16            // fused2 dst-tile
#define NTILE   3125          // 50000/16
#define NSEG    (NTILE * 16)  // 50000 (tile,rel) segments

#define CB_SH   7             // coarse bucket = dst>>7 (128 dsts)
#define NCB     391           // ceil(50000/128)
#define P1_CHUNK 4096
#define P1_GRID  391          // ceil(1.6M/4096)

#define EMAX    3200000       // 1.6M + <=50K*31 pad + slack
#define PREP_HBLK 3125        // 3.2M h elems / 1024 per block

typedef __attribute__((ext_vector_type(8))) short short8;
typedef __attribute__((ext_vector_type(4))) float float4v;
typedef __attribute__((ext_vector_type(4))) unsigned short ushort4v;

template<int IS_F32>
__device__ __forceinline__ float ldx(const void* p, size_t i) {
    if (IS_F32) {
        return ((const float*)p)[i];
    } else {
        unsigned short u = ((const unsigned short*)p)[i];
        return __uint_as_float(((unsigned)u) << 16);
    }
}

__device__ __forceinline__ float bfbits2f(unsigned short u) {
    return __uint_as_float(((unsigned)u) << 16);
}

__device__ __forceinline__ unsigned short f2bfbits(float v) {
    __hip_bfloat16 b = __float2bfloat16(v);
    unsigned short us; __builtin_memcpy(&us, &b, 2);
    return us;
}

// ---------------------------------------------------------------------------
// Dtype detector (proven): flag=1 if f32 dataset, 0 if bf16.
// ---------------------------------------------------------------------------
__global__ __launch_bounds__(1024) void k_detect(
    const float* __restrict__ norm_f, int* __restrict__ flag)
{
    __shared__ int sbad;
    if (threadIdx.x == 0) sbad = 0;
    __syncthreads();
    float v = norm_f[threadIdx.x];
    int bad = (v != v || fabsf(v) > 1e3f) ? 1 : 0;
    if (bad) atomicOr(&sbad, 1);
    __syncthreads();
    if (threadIdx.x == 0) *flag = sbad ? 0 : 1;
}

// ---------------------------------------------------------------------------
// Bucket histogram (proven pattern): coarse bucket = dst>>7.
// ---------------------------------------------------------------------------
__global__ __launch_bounds__(256) void k_bhist(
    const int* __restrict__ dst, int* __restrict__ H)
{
    __shared__ int hist[NCB];
    for (int i = threadIdx.x; i < NCB; i += 256) hist[i] = 0;
    __syncthreads();
    const int e0 = blockIdx.x * P1_CHUNK;
    for (int i = threadIdx.x; i < P1_CHUNK; i += 256) {
        int e = e0 + i;
        if (e < N_EDGES) atomicAdd(&hist[dst[e] >> CB_SH], 1);
    }
    __syncthreads();
    for (int b = threadIdx.x; b < NCB; b += 256)
        H[blockIdx.x * NCB + b] = hist[b];
}

__global__ __launch_bounds__(256) void k_bscan1(
    const int* __restrict__ H, int* __restrict__ OT, int* __restrict__ tot)
{
    __shared__ int col[P1_GRID];
    const int b = blockIdx.x;
    for (int i = threadIdx.x; i < P1_GRID; i += 256)
        col[i] = H[i * NCB + b];
    __syncthreads();
    if (threadIdx.x < 64) {
        const int lane = threadIdx.x;
        int carry = 0;
        for (int chunk = 0; chunk < (P1_GRID + 63) / 64; ++chunk) {
            int i = chunk * 64 + lane;
            int c = (i < P1_GRID) ? col[i] : 0;
            int incl = c;
#pragma unroll
            for (int off = 1; off < 64; off <<= 1) {
                int t = __shfl_up(incl, off, 64);
                if (lane >= off) incl += t;
            }
            if (i < P1_GRID) col[i] = carry + incl - c;
            carry += __shfl(incl, 63, 64);
        }
        if (lane == 0) tot[b] = carry;
    }
    __syncthreads();
    for (int i = threadIdx.x; i < P1_GRID; i += 256)
        OT[(size_t)b * P1_GRID + i] = col[i];
}

// generic 1-block exclusive scan (proven pattern), n elements
template<int N>
__device__ __forceinline__ void scan1_body(
    const int* __restrict__ in, int* __restrict__ outB, int pad32)
{
    const int lane = threadIdx.x;
    int carry = 0;
    for (int chunk = 0; chunk < (N + 63) / 64; ++chunk) {
        int i = chunk * 64 + lane;
        int c = (i < N) ? in[i] : 0;
        if (pad32) c = (c + 31) & ~31;
        int incl = c;
#pragma unroll
        for (int off = 1; off < 64; off <<= 1) {
            int t = __shfl_up(incl, off, 64);
            if (lane >= off) incl += t;
        }
        if (i < N) outB[i] = carry + incl - c;
        carry += __shfl(incl, 63, 64);
    }
    if (lane == 0) outB[N] = carry;
}

__global__ __launch_bounds__(64) void k_bscan2(
    const int* __restrict__ tot, int* __restrict__ base)
{
    scan1_body<NCB>(tot, base, 0);
}

__global__ __launch_bounds__(64) void k_cscan(
    const int* __restrict__ padTot, int* __restrict__ cbase)
{
    scan1_body<NCB>(padTot, cbase, 0);   // padTot already 32-multiples
}

// ---------------------------------------------------------------------------
// P1 (proven): multisplit into coarse bucket runs, deterministic reservation.
// rec: [6:0]=dst&127, [23:8]=src, [27:24]=rel, [47:32]=norm bf16.
// ---------------------------------------------------------------------------
template<int IS_F32>
__device__ __forceinline__ void p1_body(
    const int* __restrict__ src, const int* __restrict__ dst,
    const int* __restrict__ rel, const void* __restrict__ norm_raw,
    const int* __restrict__ base, const int* __restrict__ OT,
    unsigned long long* __restrict__ R, int* curs)
{
    const int blk = blockIdx.x;
    for (int b = threadIdx.x; b < NCB; b += 256)
        curs[b] = base[b] + OT[(size_t)b * P1_GRID + blk];
    __syncthreads();
    const int e0 = blk * P1_CHUNK;
    for (int i = threadIdx.x; i < P1_CHUNK; i += 256) {
        int e = e0 + i;
        if (e >= N_EDGES) continue;
        int d = dst[e];
        int pos = atomicAdd(&curs[d >> CB_SH], 1);
        unsigned short nb = f2bfbits(ldx<IS_F32>(norm_raw, e));
        unsigned long long rec =
              (unsigned long long)(d & 127)
            | ((unsigned long long)(unsigned)src[e] << 8)
            | ((unsigned long long)(unsigned)rel[e] << 24)
            | ((unsigned long long)nb << 32);
        R[pos] = rec;
    }
}

__global__ __launch_bounds__(256) void k_p1(
    const int* __restrict__ src, const int* __restrict__ dst,
    const int* __restrict__ rel, const void* __restrict__ norm_raw,
    const int* __restrict__ base, const int* __restrict__ OT,
    unsigned long long* __restrict__ R, const int* __restrict__ flag)
{
    __shared__ int curs[NCB];
    if (*flag) p1_body<1>(src, dst, rel, norm_raw, base, OT, R, curs);
    else       p1_body<0>(src, dst, rel, norm_raw, base, OT, R, curs);
}

// ---------------------------------------------------------------------------
// FINEA: per coarse bucket, LDS-hist the 128 fine bins (rel*8 + tile_local)
// and emit padded (x32) bucket total.
// ---------------------------------------------------------------------------
__global__ __launch_bounds__(256) void k_fineA(
    const int* __restrict__ base,
    const unsigned long long* __restrict__ R,
    int* __restrict__ fineCnt, int* __restrict__ padTot)
{
    __shared__ int cnt[128];
    const int tid = threadIdx.x;
    if (tid < 128) cnt[tid] = 0;
    __syncthreads();
    const int cb = blockIdx.x;
    const int c0 = base[cb], c1 = base[cb + 1];
    for (int i = c0 + tid; i < c1; i += 256) {
        unsigned long long rec = R[i];
        int bin = (int)((rec >> 24) & 15) * 8 + (int)((rec >> 4) & 7);
        atomicAdd(&cnt[bin], 1);
    }
    __syncthreads();
    if (tid < 128) fineCnt[cb * 128 + tid] = cnt[tid];
    if (tid == 0) {
        int s = 0;
        for (int j = 0; j < 128; ++j) s += (cnt[j] + 31) & ~31;
        padTot[cb] = s;
    }
}

// ---------------------------------------------------------------------------
// PLACE: per coarse bucket, exact placement into the padded global arena.
// Also writes segBase/segCnt in fused2's (tile*16 + rel) indexing and zeros
// pad slots in-place (no global zero pass needed).
// ---------------------------------------------------------------------------
__global__ __launch_bounds__(256) void k_place(
    const int* __restrict__ base,
    const unsigned long long* __restrict__ R,
    const int* __restrict__ fineCnt, const int* __restrict__ cbase,
    unsigned* __restrict__ packed2, unsigned short* __restrict__ normS,
    int* __restrict__ segBase, int* __restrict__ segCnt)
{
    __shared__ int sbl[128], curs[128], cntL[128];
    const int tid = threadIdx.x;
    const int cb = blockIdx.x;
    if (tid < 128) { cntL[tid] = fineCnt[cb * 128 + tid]; curs[tid] = 0; }
    __syncthreads();
    if (tid == 0) {
        int g = cbase[cb];
        for (int j = 0; j < 128; ++j) {
            sbl[j] = g;
            g += (cntL[j] + 31) & ~31;
        }
    }
    __syncthreads();
    if (tid < 128) {
        int r = tid >> 3, tl = tid & 7;
        int seg = ((cb * 8 + tl) * 16) + r;   // tile = cb*8+tl
        segBase[seg] = sbl[tid];
        segCnt[seg]  = cntL[tid];
    }

    const int c0 = base[cb], c1 = base[cb + 1];
    for (int i = c0 + tid; i < c1; i += 256) {
        unsigned long long rec = R[i];
        int bin = (int)((rec >> 24) & 15) * 8 + (int)((rec >> 4) & 7);
        int pos = sbl[bin] + atomicAdd(&curs[bin], 1);
        packed2[pos] = (unsigned)rec & 0x00FFFF0Fu;   // (dst&15) | (src<<8)
        normS[pos]   = (unsigned short)(rec >> 32);
    }
    __syncthreads();

    // zero pads: <=31 per bin, 128 bins
    for (int p = tid; p < 128 * 32; p += 256) {
        int bin = p >> 5, j = p & 31;
        int c = cntL[bin], pe = (c + 31) & ~31;
        if (j < pe - c) {
            int pos = sbl[bin] + c + j;
            packed2[pos] = 0;
            normS[pos]   = 0;
        }
    }
}

// ---------------------------------------------------------------------------
// PREP (proven): h -> bf16 copy (6.4 MB gather target) and W -> pre-swizzled
// bf16 B-fragment layout (stride 40).
// ---------------------------------------------------------------------------
__global__ __launch_bounds__(256) void k_prep(
    const void* __restrict__ h_raw, const void* __restrict__ w_raw,
    unsigned short* __restrict__ hbf, unsigned short* __restrict__ Wswz,
    const int* __restrict__ flag)
{
    const int f = *flag;
    const int blk = blockIdx.x;
    if (blk < PREP_HBLK) {
        int i0 = blk * 1024 + threadIdx.x * 4;
        if (f) {
            float4 v = *(const float4*)((const float*)h_raw + i0);
            ushort4v o;
            o[0] = f2bfbits(v.x); o[1] = f2bfbits(v.y);
            o[2] = f2bfbits(v.z); o[3] = f2bfbits(v.w);
            *(ushort4v*)(hbf + i0) = o;
        } else {
            *(uint2*)(hbf + i0) = *(const uint2*)((const unsigned short*)h_raw + i0);
        }
    } else {
        int rel = blk - PREP_HBLK;
        for (int idx = threadIdx.x; idx < 4096; idx += 256) {
            int d = idx >> 6, o = idx & 63;
            float wv = f ? ((const float*)w_raw)[(size_t)((rel << 6) + d) * 64 + o]
                         : bfbits2f(((const unsigned short*)w_raw)[(size_t)((rel << 6) + d) * 64 + o]);
            int c = d >> 5, q = (d >> 3) & 3, j = d & 7;
            Wswz[(size_t)rel * 5120 + ((c << 6) + o) * 40 + q * 8 + j] = f2bfbits(wv);
        }
    }
}

// ---------------------------------------------------------------------------
// K_FUSED2 (proven in R4, byte-identical): one wave per 16-dst tile.
//   s[16x64] = sum_chunks P[16x32] x H[32x64]   (P = norm selector; MFMA does
//   the dst-scatter; H rows gathered as 2B loads from 6.4MB L2-scale hbf)
//   out_tile += s @ W_r                          (8 MFMAs, reg accumulation)
// Zero atomics.
// ---------------------------------------------------------------------------
#define MFMA_BF16 __builtin_amdgcn_mfma_f32_16x16x32_bf16

__global__ __launch_bounds__(256) void k_fused2(
    const unsigned* __restrict__ packed2,
    const unsigned short* __restrict__ normS,
    const unsigned short* __restrict__ hbf,
    const unsigned short* __restrict__ Wswz,
    const int* __restrict__ segBase,
    const int* __restrict__ segCnt,
    void* __restrict__ out, const int* __restrict__ flag)
{
    __shared__ __align__(16) unsigned short sbuf[4][16 * 72];
    const int tid  = threadIdx.x;
    const int lane = tid & 63, wave = tid >> 6;
    const int n15  = lane & 15, quad = lane >> 4;
    const int tile = blockIdx.x * 4 + wave;
    if (tile >= NTILE) return;

    float4v ac0 = {0.f,0.f,0.f,0.f}, ac1 = {0.f,0.f,0.f,0.f};
    float4v ac2 = {0.f,0.f,0.f,0.f}, ac3 = {0.f,0.f,0.f,0.f};
    unsigned short* sb_ = &sbuf[wave][0];

    for (int r = 0; r < NREL; ++r) {
        const int sgb  = segBase[tile * 16 + r];
        const int scnt = segCnt[tile * 16 + r];
        if (scnt == 0) continue;
        const int nch = (scnt + 31) >> 5;

        float4v s0 = {0.f,0.f,0.f,0.f}, s1 = {0.f,0.f,0.f,0.f};
        float4v s2 = {0.f,0.f,0.f,0.f}, s3 = {0.f,0.f,0.f,0.f};

        for (int c = 0; c < nch; ++c) {
            const int e0 = sgb + (c << 5) + (quad << 3);
            const uint4 pa = *(const uint4*)(packed2 + e0);
            const uint4 pb = *(const uint4*)(packed2 + e0 + 4);
            const ushort4v na = *(const ushort4v*)(normS + e0);
            const ushort4v nb = *(const ushort4v*)(normS + e0 + 4);

            const unsigned short* h0 = hbf + (size_t)(pa.x >> 8) * 64 + n15;
            const unsigned short* h1 = hbf + (size_t)(pa.y >> 8) * 64 + n15;
            const unsigned short* h2 = hbf + (size_t)(pa.z >> 8) * 64 + n15;
            const unsigned short* h3 = hbf + (size_t)(pa.w >> 8) * 64 + n15;
            const unsigned short* h4 = hbf + (size_t)(pb.x >> 8) * 64 + n15;
            const unsigned short* h5 = hbf + (size_t)(pb.y >> 8) * 64 + n15;
            const unsigned short* h6 = hbf + (size_t)(pb.z >> 8) * 64 + n15;
            const unsigned short* h7 = hbf + (size_t)(pb.w >> 8) * 64 + n15;

            short8 av;
            av[0] = ((int)(pa.x & 15u) == n15) ? (short)na[0] : (short)0;
            av[1] = ((int)(pa.y & 15u) == n15) ? (short)na[1] : (short)0;
            av[2] = ((int)(pa.z & 15u) == n15) ? (short)na[2] : (short)0;
            av[3] = ((int)(pa.w & 15u) == n15) ? (short)na[3] : (short)0;
            av[4] = ((int)(pb.x & 15u) == n15) ? (short)nb[0] : (short)0;
            av[5] = ((int)(pb.y & 15u) == n15) ? (short)nb[1] : (short)0;
            av[6] = ((int)(pb.z & 15u) == n15) ? (short)nb[2] : (short)0;
            av[7] = ((int)(pb.w & 15u) == n15) ? (short)nb[3] : (short)0;

#define GATHER_MFMA(S, OFF) \
            { short8 bv; \
              bv[0] = (short)h0[OFF]; bv[1] = (short)h1[OFF]; \
              bv[2] = (short)h2[OFF]; bv[3] = (short)h3[OFF]; \
              bv[4] = (short)h4[OFF]; bv[5] = (short)h5[OFF]; \
              bv[6] = (short)h6[OFF]; bv[7] = (short)h7[OFF]; \
              S = MFMA_BF16(av, bv, S, 0, 0, 0); }

            GATHER_MFMA(s0, 0)
            GATHER_MFMA(s1, 16)
            GATHER_MFMA(s2, 32)
            GATHER_MFMA(s3, 48)
#undef GATHER_MFMA
        }

        // repack s (C layout: row=quad*4+i, col=t*16+n15) -> LDS row-major
#pragma unroll
        for (int i = 0; i < 4; ++i) {
            sb_[(quad * 4 + i) * 72 +  0 + n15] = f2bfbits(s0[i]);
            sb_[(quad * 4 + i) * 72 + 16 + n15] = f2bfbits(s1[i]);
            sb_[(quad * 4 + i) * 72 + 32 + n15] = f2bfbits(s2[i]);
            sb_[(quad * 4 + i) * 72 + 48 + n15] = f2bfbits(s3[i]);
        }

        // A-frags: row=n15, k-chunk=quad (k1-proven layout)
        const short8 a0 = *(const short8*)(sb_ + n15 * 72 + quad * 8);
        const short8 a1 = *(const short8*)(sb_ + n15 * 72 + 32 + quad * 8);

        const unsigned short* wp = Wswz + (size_t)r * 5120;
        const short8 w00 = *(const short8*)(wp + ( 0 + n15) * 40 + quad * 8);
        const short8 w01 = *(const short8*)(wp + (16 + n15) * 40 + quad * 8);
        const short8 w02 = *(const short8*)(wp + (32 + n15) * 40 + quad * 8);
        const short8 w03 = *(const short8*)(wp + (48 + n15) * 40 + quad * 8);
        const short8 w10 = *(const short8*)(wp + (64 + n15) * 40 + quad * 8);
        const short8 w11 = *(const short8*)(wp + (80 + n15) * 40 + quad * 8);
        const short8 w12 = *(const short8*)(wp + (96 + n15) * 40 + quad * 8);
        const short8 w13 = *(const short8*)(wp + (112 + n15) * 40 + quad * 8);

        ac0 = MFMA_BF16(a0, w00, ac0, 0, 0, 0);
        ac1 = MFMA_BF16(a0, w01, ac1, 0, 0, 0);
        ac2 = MFMA_BF16(a0, w02, ac2, 0, 0, 0);
        ac3 = MFMA_BF16(a0, w03, ac3, 0, 0, 0);
        ac0 = MFMA_BF16(a1, w10, ac0, 0, 0, 0);
        ac1 = MFMA_BF16(a1, w11, ac1, 0, 0, 0);
        ac2 = MFMA_BF16(a1, w12, ac2, 0, 0, 0);
        ac3 = MFMA_BF16(a1, w13, ac3, 0, 0, 0);
    }

    const int node0 = tile << 4;
    const int f = *flag;
#define STORE_T(AC, T) \
    { \
        _Pragma("unroll") \
        for (int i = 0; i < 4; ++i) { \
            float rv = fmaxf(AC[i], 0.f); \
            size_t ob = (size_t)(node0 + quad * 4 + i) * 64 + (T) * 16 + n15; \
            if (f) ((float*)out)[ob] = rv; \
            else   ((unsigned short*)out)[ob] = f2bfbits(rv); \
        } \
    }
    STORE_T(ac0, 0)
    STORE_T(ac1, 1)
    STORE_T(ac2, 2)
    STORE_T(ac3, 3)
#undef STORE_T
}

// ---------------------------------------------------------------------------
extern "C" void kernel_launch(void* const* d_in, const int* in_sizes, int n_in,
                              void* d_out, int out_size, void* d_ws, size_t ws_size,
                              hipStream_t stream)
{
    const void* h      = d_in[0];
    const void* weight = d_in[1];
    const void* norm   = d_in[2];
    const int* src = (const int*)d_in[3];
    const int* dst = (const int*)d_in[4];
    const int* rel = (const int*)d_in[5];

    char* w = (char*)d_ws;
    int* flag = (int*)w;                        w += 256;
    int* base = (int*)w;                        w += ((NCB + 1) * 4 + 255) / 256 * 256;
    int* tot  = (int*)w;                        w += (NCB * 4 + 255) / 256 * 256;
    int* padTot = (int*)w;                      w += (NCB * 4 + 255) / 256 * 256;
    int* cbase  = (int*)w;                      w += ((NCB + 1) * 4 + 255) / 256 * 256;
    int* H    = (int*)w;                        w += ((size_t)P1_GRID * NCB * 4 + 255) / 256 * 256;
    int* OT   = (int*)w;                        w += ((size_t)NCB * P1_GRID * 4 + 255) / 256 * 256;
    int* fineCnt = (int*)w;                     w += ((size_t)NCB * 128 * 4 + 255) / 256 * 256;
    int* segBase = (int*)w;                     w += ((size_t)(NSEG + 1) * 4 + 255) / 256 * 256;
    int* segCnt  = (int*)w;                     w += ((size_t)NSEG * 4 + 255) / 256 * 256;
    unsigned long long* R = (unsigned long long*)w;  w += (size_t)N_EDGES * 8;
    unsigned* packed2 = (unsigned*)w;           w += ((size_t)EMAX * 4 + 255) / 256 * 256;
    unsigned short* normS = (unsigned short*)w; w += ((size_t)EMAX * 2 + 255) / 256 * 256;
    unsigned short* hbf = (unsigned short*)w;   w += (size_t)N_NODES * DIM * 2;
    unsigned short* Wswz = (unsigned short*)w;  w += (size_t)NREL * 5120 * 2;

    k_detect<<<1, 1024, 0, stream>>>((const float*)norm, flag);

    k_bhist<<<P1_GRID, 256, 0, stream>>>(dst, H);
    k_bscan1<<<NCB, 256, 0, stream>>>(H, OT, tot);
    k_bscan2<<<1, 64, 0, stream>>>(tot, base);

    k_p1<<<P1_GRID, 256, 0, stream>>>(src, dst, rel, norm, base, OT, R, flag);

    k_fineA<<<NCB, 256, 0, stream>>>(base, R, fineCnt, padTot);
    k_cscan<<<1, 64, 0, stream>>>(padTot, cbase);
    k_place<<<NCB, 256, 0, stream>>>(base, R, fineCnt, cbase,
                                     packed2, normS, segBase, segCnt);

    k_prep<<<PREP_HBLK + NREL, 256, 0, stream>>>(h, weight, hbf, Wswz, flag);

    k_fused2<<<(NTILE + 3) / 4, 256, 0, stream>>>(packed2, normS, hbf, Wswz,
                                                  segBase, segCnt, d_out, flag);
}

// Round 7
// 210.401 us; speedup vs baseline: 1.8778x; 1.1056x over previous
//
#include <hip/hip_runtime.h>
#include <hip/hip_bf16.h>

#define N_NODES 50000
#define N_EDGES 1600000
#define NREL    16
#define DIM     64

#define BKT_SZ  16            // fused2 dst-tile
#define NTILE   3125          // 50000/16
#define NSEG_AL 50049         // max seg index 50047 (cb=390,tl=7) + 1

#define CB_SH   7             // coarse bucket = dst>>7 (128 dsts)
#define NCB     391           // ceil(50000/128)
#define P1_CHUNK 2048
#define P1_GRID  782          // ceil(1.6M/2048)  (R0-proven balance)

#define CB_ARENA 8704         // fixed per-cb arena: max run ~4400 + 128*31 pad
#define EMAX    (NCB * CB_ARENA)   // 3,403,264 slots
#define PREP_HBLK 3125        // 3.2M h elems / 1024 per block

typedef __attribute__((ext_vector_type(8))) short short8;
typedef __attribute__((ext_vector_type(4))) float float4v;
typedef __attribute__((ext_vector_type(4))) unsigned short ushort4v;

template<int IS_F32>
__device__ __forceinline__ float ldx(const void* p, size_t i) {
    if (IS_F32) {
        return ((const float*)p)[i];
    } else {
        unsigned short u = ((const unsigned short*)p)[i];
        return __uint_as_float(((unsigned)u) << 16);
    }
}

__device__ __forceinline__ float bfbits2f(unsigned short u) {
    return __uint_as_float(((unsigned)u) << 16);
}

__device__ __forceinline__ unsigned short f2bfbits(float v) {
    __hip_bfloat16 b = __float2bfloat16(v);
    unsigned short us; __builtin_memcpy(&us, &b, 2);
    return us;
}

// ---------------------------------------------------------------------------
// Dtype detector (proven): flag=1 if f32 dataset, 0 if bf16.
// ---------------------------------------------------------------------------
__global__ __launch_bounds__(1024) void k_detect(
    const float* __restrict__ norm_f, int* __restrict__ flag)
{
    __shared__ int sbad;
    if (threadIdx.x == 0) sbad = 0;
    __syncthreads();
    float v = norm_f[threadIdx.x];
    int bad = (v != v || fabsf(v) > 1e3f) ? 1 : 0;
    if (bad) atomicOr(&sbad, 1);
    __syncthreads();
    if (threadIdx.x == 0) *flag = sbad ? 0 : 1;
}

// ---------------------------------------------------------------------------
// BHIST+PREP merged (both pure streaming, both only depend on detect).
// blocks [0,782): per-chunk coarse histogram. blocks [782,...): h->bf16 copy
// and W->pre-swizzled fragments.
// ---------------------------------------------------------------------------
__global__ __launch_bounds__(256) void k_bhist_prep(
    const int* __restrict__ dst, int* __restrict__ H,
    const void* __restrict__ h_raw, const void* __restrict__ w_raw,
    unsigned short* __restrict__ hbf, unsigned short* __restrict__ Wswz,
    const int* __restrict__ flag)
{
    __shared__ int hist[NCB];
    const int blk = blockIdx.x;
    if (blk < P1_GRID) {
        for (int i = threadIdx.x; i < NCB; i += 256) hist[i] = 0;
        __syncthreads();
        const int e0 = blk * P1_CHUNK;
        for (int i = threadIdx.x; i < P1_CHUNK; i += 256) {
            int e = e0 + i;
            if (e < N_EDGES) atomicAdd(&hist[dst[e] >> CB_SH], 1);
        }
        __syncthreads();
        for (int b = threadIdx.x; b < NCB; b += 256)
            H[blk * NCB + b] = hist[b];
    } else {
        const int f = *flag;
        const int blk2 = blk - P1_GRID;
        if (blk2 < PREP_HBLK) {
            int i0 = blk2 * 1024 + threadIdx.x * 4;
            if (f) {
                float4 v = *(const float4*)((const float*)h_raw + i0);
                ushort4v o;
                o[0] = f2bfbits(v.x); o[1] = f2bfbits(v.y);
                o[2] = f2bfbits(v.z); o[3] = f2bfbits(v.w);
                *(ushort4v*)(hbf + i0) = o;
            } else {
                *(uint2*)(hbf + i0) = *(const uint2*)((const unsigned short*)h_raw + i0);
            }
        } else {
            int rel = blk2 - PREP_HBLK;
            for (int idx = threadIdx.x; idx < 4096; idx += 256) {
                int d = idx >> 6, o = idx & 63;
                float wv = f ? ((const float*)w_raw)[(size_t)((rel << 6) + d) * 64 + o]
                             : bfbits2f(((const unsigned short*)w_raw)[(size_t)((rel << 6) + d) * 64 + o]);
                int c = d >> 5, q = (d >> 3) & 3, j = d & 7;
                Wswz[(size_t)rel * 5120 + ((c << 6) + o) * 40 + q * 8 + j] = f2bfbits(wv);
            }
        }
    }
}

__global__ __launch_bounds__(256) void k_bscan1(
    const int* __restrict__ H, int* __restrict__ OT, int* __restrict__ tot)
{
    __shared__ int col[P1_GRID];
    const int b = blockIdx.x;
    for (int i = threadIdx.x; i < P1_GRID; i += 256)
        col[i] = H[i * NCB + b];
    __syncthreads();
    if (threadIdx.x < 64) {
        const int lane = threadIdx.x;
        int carry = 0;
        for (int chunk = 0; chunk < (P1_GRID + 63) / 64; ++chunk) {
            int i = chunk * 64 + lane;
            int c = (i < P1_GRID) ? col[i] : 0;
            int incl = c;
#pragma unroll
            for (int off = 1; off < 64; off <<= 1) {
                int t = __shfl_up(incl, off, 64);
                if (lane >= off) incl += t;
            }
            if (i < P1_GRID) col[i] = carry + incl - c;
            carry += __shfl(incl, 63, 64);
        }
        if (lane == 0) tot[b] = carry;
    }
    __syncthreads();
    for (int i = threadIdx.x; i < P1_GRID; i += 256)
        OT[(size_t)b * P1_GRID + i] = col[i];
}

__global__ __launch_bounds__(64) void k_bscan2(
    const int* __restrict__ tot, int* __restrict__ base)
{
    const int lane = threadIdx.x;
    int carry = 0;
    for (int chunk = 0; chunk < (NCB + 63) / 64; ++chunk) {
        int i = chunk * 64 + lane;
        int c = (i < NCB) ? tot[i] : 0;
        int incl = c;
#pragma unroll
        for (int off = 1; off < 64; off <<= 1) {
            int t = __shfl_up(incl, off, 64);
            if (lane >= off) incl += t;
        }
        if (i < NCB) base[i] = carry + incl - c;
        carry += __shfl(incl, 63, 64);
    }
    if (lane == 0) base[NCB] = carry;   // == N_EDGES
}

// ---------------------------------------------------------------------------
// P1 (proven): multisplit into coarse bucket runs, deterministic reservation.
// rec: [6:0]=dst&127, [23:8]=src, [27:24]=rel, [47:32]=norm bf16.
// ---------------------------------------------------------------------------
template<int IS_F32>
__device__ __forceinline__ void p1_body(
    const int* __restrict__ src, const int* __restrict__ dst,
    const int* __restrict__ rel, const void* __restrict__ norm_raw,
    const int* __restrict__ base, const int* __restrict__ OT,
    unsigned long long* __restrict__ R, int* curs)
{
    const int blk = blockIdx.x;
    for (int b = threadIdx.x; b < NCB; b += 256)
        curs[b] = base[b] + OT[(size_t)b * P1_GRID + blk];
    __syncthreads();
    const int e0 = blk * P1_CHUNK;
    for (int i = threadIdx.x; i < P1_CHUNK; i += 256) {
        int e = e0 + i;
        if (e >= N_EDGES) continue;
        int d = dst[e];
        int pos = atomicAdd(&curs[d >> CB_SH], 1);
        unsigned short nb = f2bfbits(ldx<IS_F32>(norm_raw, e));
        unsigned long long rec =
              (unsigned long long)(d & 127)
            | ((unsigned long long)(unsigned)src[e] << 8)
            | ((unsigned long long)(unsigned)rel[e] << 24)
            | ((unsigned long long)nb << 32);
        R[pos] = rec;
    }
}

__global__ __launch_bounds__(256) void k_p1(
    const int* __restrict__ src, const int* __restrict__ dst,
    const int* __restrict__ rel, const void* __restrict__ norm_raw,
    const int* __restrict__ base, const int* __restrict__ OT,
    unsigned long long* __restrict__ R, const int* __restrict__ flag)
{
    __shared__ int curs[NCB];
    if (*flag) p1_body<1>(src, dst, rel, norm_raw, base, OT, R, curs);
    else       p1_body<0>(src, dst, rel, norm_raw, base, OT, R, curs);
}

// ---------------------------------------------------------------------------
// FINE (merged fineA+cscan+place): fixed per-cb arena (cb*CB_ARENA) removes
// the global scan dependency; pass-2 R re-read is L2-hot (same block/XCD).
// ---------------------------------------------------------------------------
__global__ __launch_bounds__(256) void k_fine(
    const int* __restrict__ base,
    const unsigned long long* __restrict__ R,
    unsigned* __restrict__ packed2, unsigned short* __restrict__ normS,
    int* __restrict__ segBase, int* __restrict__ segCnt)
{
    __shared__ int cnt[128], sbl[128], curs[128];
    const int tid = threadIdx.x, cb = blockIdx.x;
    if (tid < 128) { cnt[tid] = 0; curs[tid] = 0; }
    __syncthreads();
    const int c0 = base[cb], c1 = base[cb + 1];

    for (int i = c0 + tid; i < c1; i += 256) {
        unsigned long long rec = R[i];
        int bin = (int)((rec >> 24) & 15) * 8 + (int)((rec >> 4) & 7);
        atomicAdd(&cnt[bin], 1);
    }
    __syncthreads();

    if (tid == 0) {
        int g = cb * CB_ARENA;
        for (int j = 0; j < 128; ++j) {
            sbl[j] = g;
            g += (cnt[j] + 31) & ~31;
        }
    }
    __syncthreads();

    if (tid < 128) {
        int seg = ((cb * 8 + (tid & 7)) << 4) + (tid >> 3);   // tile*16 + rel
        segBase[seg] = sbl[tid];
        segCnt[seg]  = cnt[tid];
    }

    for (int i = c0 + tid; i < c1; i += 256) {
        unsigned long long rec = R[i];
        int bin = (int)((rec >> 24) & 15) * 8 + (int)((rec >> 4) & 7);
        int pos = sbl[bin] + atomicAdd(&curs[bin], 1);
        packed2[pos] = (unsigned)rec & 0x00FFFF0Fu;   // (dst&15) | (src<<8)
        normS[pos]   = (unsigned short)(rec >> 32);
    }
    __syncthreads();

    for (int p = tid; p < 128 * 32; p += 256) {
        int bin = p >> 5, j = p & 31;
        int c = cnt[bin], pe = (c + 31) & ~31;
        if (j < pe - c) {
            int pos = sbl[bin] + c + j;
            packed2[pos] = 0;
            normS[pos]   = 0;
        }
    }
}

// ---------------------------------------------------------------------------
// K_FUSED2 v3: TWO waves per 16-dst tile (rel halves 0-7 / 8-15) to double
// resident waves (3125 -> 6250, ~24/CU). Partial C merged via LDS
// (stride-17 floats, conflict-free). Inner body identical to R4-proven.
// ---------------------------------------------------------------------------
#define MFMA_BF16 __builtin_amdgcn_mfma_f32_16x16x32_bf16

__global__ __launch_bounds__(256) void k_fused2(
    const unsigned* __restrict__ packed2,
    const unsigned short* __restrict__ normS,
    const unsigned short* __restrict__ hbf,
    const unsigned short* __restrict__ Wswz,
    const int* __restrict__ segBase,
    const int* __restrict__ segCnt,
    void* __restrict__ out, const int* __restrict__ flag)
{
    __shared__ __align__(16) unsigned short sbuf[4][16 * 72];
    __shared__ float pbuf[2][64][17];
    const int tid  = threadIdx.x;
    const int lane = tid & 63, wave = tid >> 6;
    const int n15  = lane & 15, quad = lane >> 4;
    const int tin  = wave >> 1;          // tile within block
    const int half = wave & 1;           // rel half
    const int tile = blockIdx.x * 2 + tin;
    const bool valid = (tile < NTILE);

    float4v ac0 = {0.f,0.f,0.f,0.f}, ac1 = {0.f,0.f,0.f,0.f};
    float4v ac2 = {0.f,0.f,0.f,0.f}, ac3 = {0.f,0.f,0.f,0.f};
    unsigned short* sb_ = &sbuf[wave][0];

    if (valid) {
        const int r0 = half * 8;
        for (int r = r0; r < r0 + 8; ++r) {
            const int sgb  = segBase[tile * 16 + r];
            const int scnt = segCnt[tile * 16 + r];
            if (scnt == 0) continue;
            const int nch = (scnt + 31) >> 5;

            float4v s0 = {0.f,0.f,0.f,0.f}, s1 = {0.f,0.f,0.f,0.f};
            float4v s2 = {0.f,0.f,0.f,0.f}, s3 = {0.f,0.f,0.f,0.f};

            for (int c = 0; c < nch; ++c) {
                const int e0 = sgb + (c << 5) + (quad << 3);
                const uint4 pa = *(const uint4*)(packed2 + e0);
                const uint4 pb = *(const uint4*)(packed2 + e0 + 4);
                const ushort4v na = *(const ushort4v*)(normS + e0);
                const ushort4v nb = *(const ushort4v*)(normS + e0 + 4);

                const unsigned short* h0 = hbf + (size_t)(pa.x >> 8) * 64 + n15;
                const unsigned short* h1 = hbf + (size_t)(pa.y >> 8) * 64 + n15;
                const unsigned short* h2 = hbf + (size_t)(pa.z >> 8) * 64 + n15;
                const unsigned short* h3 = hbf + (size_t)(pa.w >> 8) * 64 + n15;
                const unsigned short* h4 = hbf + (size_t)(pb.x >> 8) * 64 + n15;
                const unsigned short* h5 = hbf + (size_t)(pb.y >> 8) * 64 + n15;
                const unsigned short* h6 = hbf + (size_t)(pb.z >> 8) * 64 + n15;
                const unsigned short* h7 = hbf + (size_t)(pb.w >> 8) * 64 + n15;

                short8 av;
                av[0] = ((int)(pa.x & 15u) == n15) ? (short)na[0] : (short)0;
                av[1] = ((int)(pa.y & 15u) == n15) ? (short)na[1] : (short)0;
                av[2] = ((int)(pa.z & 15u) == n15) ? (short)na[2] : (short)0;
                av[3] = ((int)(pa.w & 15u) == n15) ? (short)na[3] : (short)0;
                av[4] = ((int)(pb.x & 15u) == n15) ? (short)nb[0] : (short)0;
                av[5] = ((int)(pb.y & 15u) == n15) ? (short)nb[1] : (short)0;
                av[6] = ((int)(pb.z & 15u) == n15) ? (short)nb[2] : (short)0;
                av[7] = ((int)(pb.w & 15u) == n15) ? (short)nb[3] : (short)0;

#define GATHER_MFMA(S, OFF) \
                { short8 bv; \
                  bv[0] = (short)h0[OFF]; bv[1] = (short)h1[OFF]; \
                  bv[2] = (short)h2[OFF]; bv[3] = (short)h3[OFF]; \
                  bv[4] = (short)h4[OFF]; bv[5] = (short)h5[OFF]; \
                  bv[6] = (short)h6[OFF]; bv[7] = (short)h7[OFF]; \
                  S = MFMA_BF16(av, bv, S, 0, 0, 0); }

                GATHER_MFMA(s0, 0)
                GATHER_MFMA(s1, 16)
                GATHER_MFMA(s2, 32)
                GATHER_MFMA(s3, 48)
#undef GATHER_MFMA
            }

            // repack s (C layout: row=quad*4+i, col=t*16+n15) -> LDS row-major
#pragma unroll
            for (int i = 0; i < 4; ++i) {
                sb_[(quad * 4 + i) * 72 +  0 + n15] = f2bfbits(s0[i]);
                sb_[(quad * 4 + i) * 72 + 16 + n15] = f2bfbits(s1[i]);
                sb_[(quad * 4 + i) * 72 + 32 + n15] = f2bfbits(s2[i]);
                sb_[(quad * 4 + i) * 72 + 48 + n15] = f2bfbits(s3[i]);
            }

            // A-frags: row=n15, k-chunk=quad (k1-proven layout)
            const short8 a0 = *(const short8*)(sb_ + n15 * 72 + quad * 8);
            const short8 a1 = *(const short8*)(sb_ + n15 * 72 + 32 + quad * 8);

            const unsigned short* wp = Wswz + (size_t)r * 5120;
            const short8 w00 = *(const short8*)(wp + ( 0 + n15) * 40 + quad * 8);
            const short8 w01 = *(const short8*)(wp + (16 + n15) * 40 + quad * 8);
            const short8 w02 = *(const short8*)(wp + (32 + n15) * 40 + quad * 8);
            const short8 w03 = *(const short8*)(wp + (48 + n15) * 40 + quad * 8);
            const short8 w10 = *(const short8*)(wp + (64 + n15) * 40 + quad * 8);
            const short8 w11 = *(const short8*)(wp + (80 + n15) * 40 + quad * 8);
            const short8 w12 = *(const short8*)(wp + (96 + n15) * 40 + quad * 8);
            const short8 w13 = *(const short8*)(wp + (112 + n15) * 40 + quad * 8);

            ac0 = MFMA_BF16(a0, w00, ac0, 0, 0, 0);
            ac1 = MFMA_BF16(a0, w01, ac1, 0, 0, 0);
            ac2 = MFMA_BF16(a0, w02, ac2, 0, 0, 0);
            ac3 = MFMA_BF16(a0, w03, ac3, 0, 0, 0);
            ac0 = MFMA_BF16(a1, w10, ac0, 0, 0, 0);
            ac1 = MFMA_BF16(a1, w11, ac1, 0, 0, 0);
            ac2 = MFMA_BF16(a1, w12, ac2, 0, 0, 0);
            ac3 = MFMA_BF16(a1, w13, ac3, 0, 0, 0);
        }
    }

    // merge rel halves: odd wave publishes, even wave reduces + stores.
    if (half) {
#pragma unroll
        for (int i = 0; i < 4; ++i) {
            pbuf[tin][lane][i]      = ac0[i];
            pbuf[tin][lane][4 + i]  = ac1[i];
            pbuf[tin][lane][8 + i]  = ac2[i];
            pbuf[tin][lane][12 + i] = ac3[i];
        }
    }
    __syncthreads();
    if (!half && valid) {
#pragma unroll
        for (int i = 0; i < 4; ++i) {
            ac0[i] += pbuf[tin][lane][i];
            ac1[i] += pbuf[tin][lane][4 + i];
            ac2[i] += pbuf[tin][lane][8 + i];
            ac3[i] += pbuf[tin][lane][12 + i];
        }
        const int node0 = tile << 4;
        const int f = *flag;
#define STORE_T(AC, T) \
        { \
            _Pragma("unroll") \
            for (int i = 0; i < 4; ++i) { \
                float rv = fmaxf(AC[i], 0.f); \
                size_t ob = (size_t)(node0 + quad * 4 + i) * 64 + (T) * 16 + n15; \
                if (f) ((float*)out)[ob] = rv; \
                else   ((unsigned short*)out)[ob] = f2bfbits(rv); \
            } \
        }
        STORE_T(ac0, 0)
        STORE_T(ac1, 1)
        STORE_T(ac2, 2)
        STORE_T(ac3, 3)
#undef STORE_T
    }
}

// ---------------------------------------------------------------------------
extern "C" void kernel_launch(void* const* d_in, const int* in_sizes, int n_in,
                              void* d_out, int out_size, void* d_ws, size_t ws_size,
                              hipStream_t stream)
{
    const void* h      = d_in[0];
    const void* weight = d_in[1];
    const void* norm   = d_in[2];
    const int* src = (const int*)d_in[3];
    const int* dst = (const int*)d_in[4];
    const int* rel = (const int*)d_in[5];

    char* w = (char*)d_ws;
    int* flag = (int*)w;                        w += 256;
    int* base = (int*)w;                        w += ((NCB + 1) * 4 + 255) / 256 * 256;
    int* tot  = (int*)w;                        w += (NCB * 4 + 255) / 256 * 256;
    int* H    = (int*)w;                        w += ((size_t)P1_GRID * NCB * 4 + 255) / 256 * 256;
    int* OT   = (int*)w;                        w += ((size_t)NCB * P1_GRID * 4 + 255) / 256 * 256;
    int* segBase = (int*)w;                     w += ((size_t)NSEG_AL * 4 + 255) / 256 * 256;
    int* segCnt  = (int*)w;                     w += ((size_t)NSEG_AL * 4 + 255) / 256 * 256;
    unsigned long long* R = (unsigned long long*)w;  w += (size_t)N_EDGES * 8;
    unsigned* packed2 = (unsigned*)w;           w += ((size_t)EMAX * 4 + 255) / 256 * 256;
    unsigned short* normS = (unsigned short*)w; w += ((size_t)EMAX * 2 + 255) / 256 * 256;
    unsigned short* hbf = (unsigned short*)w;   w += (size_t)N_NODES * DIM * 2;
    unsigned short* Wswz = (unsigned short*)w;  w += (size_t)NREL * 5120 * 2;

    k_detect<<<1, 1024, 0, stream>>>((const float*)norm, flag);

    k_bhist_prep<<<P1_GRID + PREP_HBLK + NREL, 256, 0, stream>>>(
        dst, H, h, weight, hbf, Wswz, flag);

    k_bscan1<<<NCB, 256, 0, stream>>>(H, OT, tot);
    k_bscan2<<<1, 64, 0, stream>>>(tot, base);

    k_p1<<<P1_GRID, 256, 0, stream>>>(src, dst, rel, norm, base, OT, R, flag);

    k_fine<<<NCB, 256, 0, stream>>>(base, R, packed2, normS, segBase, segCnt);

    k_fused2<<<(NTILE + 1) / 2, 256, 0, stream>>>(packed2, normS, hbf, Wswz,
                                                  segBase, segCnt, d_out, flag);
}